// Round 8
// baseline (1280.981 us; speedup 1.0000x reference)
//
#include <hip/hip_runtime.h>
#include <hip/hip_bf16.h>
#include <stdint.h>

#define D_DIM 1024
#define N_DIM 4096
#define C_CLS 10
#define L_IT 8
#define M_DIM 11264   // (C+1)*D
#define NBM 44        // M_DIM / 256

typedef __bf16 bf16_t;
typedef __bf16 bf16x8 __attribute__((ext_vector_type(8)));
typedef __bf16 bf16x4 __attribute__((ext_vector_type(4)));
typedef float  f32x4  __attribute__((ext_vector_type(4)));
typedef unsigned short u16x8 __attribute__((ext_vector_type(8)));

__device__ __forceinline__ float bf2f(uint16_t u) {
  union { uint32_t i; float f; } x; x.i = ((uint32_t)u) << 16; return x.f;
}

// ---------------- pack W = [Cs ; E] fp32 -> bf16 ----------------
__global__ __launch_bounds__(256) void pack_w(const float4* __restrict__ Cs,
                                              const float4* __restrict__ El,
                                              bf16x4* __restrict__ dst) {
  const int CS4 = C_CLS * D_DIM * D_DIM / 4;
  int i = blockIdx.x * 256 + threadIdx.x;
  float4 v = (i < CS4) ? Cs[i] : El[i - CS4];
  bf16x4 o;
  o[0] = (bf16_t)v.x; o[1] = (bf16_t)v.y; o[2] = (bf16_t)v.z; o[3] = (bf16_t)v.w;
  dst[i] = o;
}

// ---------------- layer-0 init ----------------
__global__ __launch_bounds__(256) void init_zt(const float* __restrict__ Zin,
                                               float* __restrict__ ZfT,
                                               bf16_t* __restrict__ ZbT) {
  __shared__ float tile[32][33];
  int tx = threadIdx.x & 31, ty = threadIdx.x >> 5;
  int nb = blockIdx.x, db = blockIdx.y;
  int n = nb * 32 + tx;
#pragma unroll
  for (int j = 0; j < 32; j += 8) {
    int d = db * 32 + ty + j;
    tile[ty + j][tx] = Zin[(size_t)d * N_DIM + n];
  }
  __syncthreads();
  int d2 = db * 32 + tx;
#pragma unroll
  for (int j = 0; j < 32; j += 8) {
    int n2 = nb * 32 + ty + j;
    float v = tile[tx][ty + j];
    ZfT[(size_t)n2 * D_DIM + d2] = v;
    ZbT[(size_t)n2 * D_DIM + d2] = (bf16_t)v;
  }
}

// ---------------- final transpose-out ----------------
__global__ __launch_bounds__(256) void final_out(const float* __restrict__ ZfT,
                                                 float* __restrict__ outp) {
  __shared__ float tile[32][33];
  int tx = threadIdx.x & 31, ty = threadIdx.x >> 5;
  int nb = blockIdx.x, db = blockIdx.y;
#pragma unroll
  for (int j = 0; j < 32; j += 8) {
    int n = nb * 32 + ty + j;
    int d = db * 32 + tx;
    tile[ty + j][tx] = ZfT[(size_t)n * D_DIM + d];
  }
  __syncthreads();
#pragma unroll
  for (int j = 0; j < 32; j += 8) {
    int d2 = db * 32 + ty + j;
    int n2 = nb * 32 + tx;
    outp[(size_t)d2 * N_DIM + n2] = tile[tx][ty + j];
  }
}

// ================= persistent 256x256 GEMM: 256 blocks, 2-3 tiles each =================
// OUT_T[col][row] = (Wb * ZbT^T)^T. 512 thr = 8 waves (2Mx4N), BK=64, K=1024 (16 K-tiles).
// XCD-chunked tiles: XCD x owns global tiles [88x, 88x+88) -> B-panels L2-resident.
// Stage ledger per iter (2 K-tiles E/O; N0/N1 = next two):
//   inv {O.A0,O.B0}=4 -> ph0 +{O.A1,O.B1} -> ph1 +{N0.A0}, vmcnt(2) -> ph2
//   +{N0.A1,N0.B0,N0.B1} -> ph3 +{N1.A0,N1.B0}, vmcnt(4) -> inv. K0 complete before
//   ph3's closing barrier; every staged region's last ds_read sealed by a prior lgkmcnt(0).
// At it==7 the N-stages target the NEXT OUTPUT TILE's K0/K1 (pipeline never drains).

#define SA(buf, h, ab, t) do {                                                          \
    _Pragma("unroll") for (int e_ = 0; e_ < 2; ++e_) {                                  \
      const bf16_t* s_ = Wb + (ab) + laneA[e_] + (size_t)(h) * 65536 + (size_t)(t) * 64;\
      __builtin_amdgcn_global_load_lds(                                                 \
        (const __attribute__((address_space(1))) void*)s_,                              \
        (__attribute__((address_space(3))) void*)(lds + (buf)*16384 + (h)*8192 + dstslot[e_]), \
        16, 0, 0);                                                                      \
    } } while (0)

#define SB(buf, h, bb, t) do {                                                          \
    _Pragma("unroll") for (int e_ = 0; e_ < 2; ++e_) {                                  \
      const bf16_t* s_ = ZbT + (bb) + laneB[e_] + (size_t)(h) * 32768 + (size_t)(t) * 64;\
      __builtin_amdgcn_global_load_lds(                                                 \
        (const __attribute__((address_space(1))) void*)s_,                              \
        (__attribute__((address_space(3))) void*)(lds + 32768 + (buf)*16384 + (h)*8192 + dstslot[e_]), \
        16, 0, 0);                                                                      \
    } } while (0)

#define LOAD_A(buf, qm) do {                                                            \
    _Pragma("unroll") for (int f_ = 0; f_ < 4; ++f_)                                    \
      _Pragma("unroll") for (int kk_ = 0; kk_ < 2; ++kk_)                               \
        a[f_][kk_] = *(const bf16x8*)(lds + (buf)*16384 + (qm)*8192 + aRowBase + f_*1024 + sidx[kk_]); \
  } while (0)

#define LOAD_Bq(buf, qn, arr) do {                                                      \
    _Pragma("unroll") for (int f_ = 0; f_ < 2; ++f_)                                    \
      _Pragma("unroll") for (int kk_ = 0; kk_ < 2; ++kk_)                               \
        arr[f_][kk_] = *(const bf16x8*)(lds + 32768 + (buf)*16384 + (qn)*8192 + bRowBase + f_*1024 + sidx[kk_]); \
  } while (0)

#define MFMAQ(qm, qn, arr) do {                                                         \
    _Pragma("unroll") for (int mm_ = 0; mm_ < 4; ++mm_)                                 \
      _Pragma("unroll") for (int nn_ = 0; nn_ < 2; ++nn_)                               \
        _Pragma("unroll") for (int kk_ = 0; kk_ < 2; ++kk_)                             \
          acc[(qm)*4+mm_][(qn)*2+nn_] = __builtin_amdgcn_mfma_f32_16x16x32_bf16(        \
            a[mm_][kk_], arr[nn_][kk_], acc[(qm)*4+mm_][(qn)*2+nn_], 0, 0, 0);          \
  } while (0)

#define BAR   __builtin_amdgcn_s_barrier()
#define SB0   __builtin_amdgcn_sched_barrier(0)
#define LGKM0 do { asm volatile("s_waitcnt lgkmcnt(0)" ::: "memory"); SB0; } while (0)
#define LGKM8 do { asm volatile("s_waitcnt lgkmcnt(8)" ::: "memory"); SB0; } while (0)
#define VM(n) asm volatile("s_waitcnt vmcnt(" #n ")" ::: "memory")
#define PRIO1 __builtin_amdgcn_s_setprio(1)
#define PRIO0 __builtin_amdgcn_s_setprio(0)

__global__ __launch_bounds__(512, 2) void gemm_persist(const bf16_t* __restrict__ Wb,
                                                       const bf16_t* __restrict__ ZbT,
                                                       bf16_t* __restrict__ OUT_T,
                                                       float* __restrict__ ssq) {
  __shared__ __align__(16) bf16_t lds[65536];  // 128 KiB

  int bid = blockIdx.x;
  int x = bid & 7, kb = bid >> 3;
  int nt, b88;
  if (kb < 24) { b88 = 3 * kb; nt = 3; }
  else         { b88 = 72 + 2 * (kb - 24); nt = 2; }
  int m0s[3], n0s[3];
  size_t tA[3], tB[3];
#pragma unroll
  for (int i = 0; i < 3; ++i) {
    int g = x * 88 + b88 + (i < nt ? i : nt - 1);
    m0s[i] = (g % NBM) * 256;
    n0s[i] = (g / NBM) * 256;
    tA[i] = (size_t)m0s[i] * 1024;
    tB[i] = (size_t)n0s[i] * 1024;
  }

  int tid = threadIdx.x;
  int wave = tid >> 6, lane = tid & 63;
  int wrow = wave >> 2, wcol = wave & 3;
  int lm = lane & 15, lks = lane >> 4;
  int sw = lm & 7;

  size_t laneA[2], laneB[2];
  int dstslot[2];
#pragma unroll
  for (int e = 0; e < 2; ++e) {
    int j = e * 512 + tid;
    int rih = j >> 3, sl = j & 7;
    int sg = sl ^ (rih & 7);                       // pre-swizzled global 16B slot
    int arow = (rih & 63) + ((rih >> 6) << 7);     // A halves: {0-63,128-191}/{+64}
    int brow = (rih & 31) + ((rih >> 5) << 6);     // B halves: 32-row interleave
    laneA[e] = (size_t)arow * 1024 + sg * 8;
    laneB[e] = (size_t)brow * 1024 + sg * 8;
    dstslot[e] = e * 4096 + wave * 512;
  }

  int aRowBase = (wrow * 64 + lm) * 64;
  int bRowBase = (wcol * 32 + lm) * 64;
  int sidx[2] = { ((0 + lks) ^ sw) * 8, ((4 + lks) ^ sw) * 8 };

  f32x4 acc[8][4] = {};
  bf16x8 a[4][2], b0[2][2], b1[2][2];

  // prologue: tile0 K0 {A0,A1,B0,B1} + K1 {A0,B0}; leave {K1.A0,K1.B0} outstanding
  SA(0, 0, tA[0], 0); SA(0, 1, tA[0], 0); SB(0, 0, tB[0], 0); SB(0, 1, tB[0], 0);
  SA(1, 0, tA[0], 1); SB(1, 0, tB[0], 1);
  VM(4);
  BAR;

  for (int tt = 0; tt < nt; ++tt) {
    size_t aC = tA[tt], bC = tB[tt];
    int nx = (tt + 1 < nt) ? tt + 1 : tt;
    bool hn = (tt + 1 < nt);
    size_t aN = tA[nx], bN = tB[nx];

    for (int it = 0; it < 8; ++it) {
      int tO = 2 * it + 1, tn2 = 2 * it + 2, tm2 = 2 * it + 3;
      bool l7 = (it == 7);

      // ---- ph0: buf0 qm0 ; stage O.{A1,B1} -> buf1 h1 ----
      LOAD_A(0, 0); LOAD_Bq(0, 0, b0); LOAD_Bq(0, 1, b1);
      SA(1, 1, aC, tO); SB(1, 1, bC, tO);
      BAR; LGKM8; PRIO1; MFMAQ(0, 0, b0); LGKM0; MFMAQ(0, 1, b1); PRIO0; BAR;

      // ---- ph1: buf0 qm1 ; stage N0.A0 -> buf0 h0 ----
      LOAD_A(0, 1);
      if (!l7)      SA(0, 0, aC, tn2);
      else if (hn)  SA(0, 0, aN, 0);
      BAR; LGKM0; PRIO1; MFMAQ(1, 0, b0); MFMAQ(1, 1, b1); PRIO0;
      if (l7 && !hn) { VM(0); } else { VM(2); }
      BAR;

      // ---- ph2: buf1 qm0 ; stage N0.{A1,B0,B1} -> buf0 ----
      LOAD_A(1, 0); LOAD_Bq(1, 0, b0); LOAD_Bq(1, 1, b1);
      if (!l7)      { SA(0, 1, aC, tn2); SB(0, 0, bC, tn2); SB(0, 1, bC, tn2); }
      else if (hn)  { SA(0, 1, aN, 0);   SB(0, 0, bN, 0);   SB(0, 1, bN, 0);   }
      BAR; LGKM8; PRIO1; MFMAQ(0, 0, b0); LGKM0; MFMAQ(0, 1, b1); PRIO0; BAR;

      // ---- ph3: buf1 qm1 ; stage N1.{A0,B0} -> buf1 h0 ----
      LOAD_A(1, 1);
      if (!l7)      { SA(1, 0, aC, tm2); SB(1, 0, bC, tm2); }
      else if (hn)  { SA(1, 0, aN, 1);   SB(1, 0, bN, 1);   }
      BAR; LGKM0; PRIO1; MFMAQ(1, 0, b0); MFMAQ(1, 1, b1); PRIO0;
      VM(4);
      BAR;
    }

    // ---- tile epilogue: C-write (transposed) + fused ssq; drain stores; reset acc ----
    int m0 = m0s[tt], n0 = n0s[tt];
#pragma unroll
    for (int mf = 0; mf < 8; ++mf)
#pragma unroll
      for (int nf = 0; nf < 4; ++nf) {
        int col = n0 + wcol * 64 + nf * 16 + lm;
        int row = m0 + wrow * 128 + mf * 16 + lks * 4;
        bf16x4 v;
#pragma unroll
        for (int rr = 0; rr < 4; ++rr) v[rr] = (bf16_t)acc[mf][nf][rr];
        *(bf16x4*)(OUT_T + (size_t)col * M_DIM + row) = v;
      }
    if (m0 < C_CLS * 1024) {
      int c = m0 >> 10;
#pragma unroll
      for (int nf = 0; nf < 4; ++nf) {
        float v = 0.f;
#pragma unroll
        for (int mf = 0; mf < 8; ++mf)
#pragma unroll
          for (int rr = 0; rr < 4; ++rr)
            v += acc[mf][nf][rr] * acc[mf][nf][rr];
        v += __shfl_xor(v, 16);
        v += __shfl_xor(v, 32);
        if (lks == 0)
          atomicAdd(&ssq[(size_t)c * N_DIM + n0 + wcol * 64 + nf * 16 + lm], v);
      }
    }
    asm volatile("s_waitcnt vmcnt(0)" ::: "memory");   // keep stores out of the ledger
#pragma unroll
    for (int mf = 0; mf < 8; ++mf)
#pragma unroll
      for (int nf = 0; nf < 4; ++nf) acc[mf][nf] = (f32x4)(0.f);
  }
}

// ---------------- fused softmax + update + normalize + ZbT emit ----------------
__global__ __launch_bounds__(256) void update2(const bf16_t* __restrict__ OUT_T, int Nc,
                                               const float* __restrict__ ssq,
                                               const float* __restrict__ gamma,
                                               const float* __restrict__ etap,
                                               const float* __restrict__ tempr,
                                               float* __restrict__ ZfT,
                                               bf16_t* __restrict__ ZbT,
                                               int n_off) {
  int wv = threadIdx.x >> 6, lane = threadIdx.x & 63;
  int nl = blockIdx.x * 4 + wv;
  if (nl >= Nc) return;
  int n = n_off + nl;
  float eta = etap[0], invT = 1.0f / tempr[0];

  float s[C_CLS], m = -1e30f;
#pragma unroll
  for (int c = 0; c < C_CLS; ++c) {
    float sim = -sqrtf(ssq[(size_t)c * Nc + nl]);
    s[c] = sim;
    m = fmaxf(m, sim);
  }
  float sum = 0.f;
#pragma unroll
  for (int c = 0; c < C_CLS; ++c) {
    float e = __expf((s[c] - m) * invT);
    s[c] = e;
    sum += e;
  }
  float invsum = 1.0f / sum;
  float gP[C_CLS];
#pragma unroll
  for (int c = 0; c < C_CLS; ++c) gP[c] = gamma[c] * s[c] * invsum;

  const u16x8* ob = (const u16x8*)(OUT_T + (size_t)nl * M_DIM) + lane * 2;
  float term[16] = {};
#pragma unroll
  for (int c = 0; c < C_CLS; ++c) {
    u16x8 v0 = ob[c * 128], v1 = ob[c * 128 + 1];
#pragma unroll
    for (int j = 0; j < 8; ++j) {
      term[j]     += gP[c] * bf2f(v0[j]);
      term[8 + j] += gP[c] * bf2f(v1[j]);
    }
  }
  u16x8 g0 = ob[C_CLS * 128], g1 = ob[C_CLS * 128 + 1];

  const f32x4* zp = (const f32x4*)(ZfT + (size_t)n * D_DIM) + lane * 4;
  f32x4 z[4] = { zp[0], zp[1], zp[2], zp[3] };

  float zn[16];
  float ss = 0.f;
#pragma unroll
  for (int j = 0; j < 16; ++j) {
    float g = bf2f(j < 8 ? g0[j & 7] : g1[j & 7]);
    float v = z[j >> 2][j & 3] + eta * (g - term[j]);
    zn[j] = v;
    ss += v * v;
  }
#pragma unroll
  for (int k = 1; k < 64; k <<= 1) ss += __shfl_xor(ss, k);
  float inv = rsqrtf(ss);

  f32x4* zo = (f32x4*)(ZfT + (size_t)n * D_DIM) + lane * 4;
  bf16x8* bo = (bf16x8*)(ZbT + (size_t)n * D_DIM) + lane * 2;
#pragma unroll
  for (int q4 = 0; q4 < 4; ++q4) {
    f32x4 o;
#pragma unroll
    for (int j = 0; j < 4; ++j) o[j] = zn[q4 * 4 + j] * inv;
    zo[q4] = o;
  }
#pragma unroll
  for (int h = 0; h < 2; ++h) {
    bf16x8 o;
#pragma unroll
    for (int j = 0; j < 8; ++j) o[j] = (bf16_t)(zn[h * 8 + j] * inv);
    bo[h] = o;
  }
}

extern "C" void kernel_launch(void* const* d_in, const int* in_sizes, int n_in,
                              void* d_out, int out_size, void* d_ws, size_t ws_size,
                              hipStream_t stream) {
  (void)in_sizes; (void)n_in; (void)out_size;
  const float* Zin        = (const float*)d_in[0];
  const float* Elist      = (const float*)d_in[1];
  const float* Cslist     = (const float*)d_in[2];
  const float* gamma      = (const float*)d_in[3];
  const float* eta        = (const float*)d_in[4];
  const float* temperature= (const float*)d_in[5];

  auto align256 = [](size_t x) { return (x + 255) & ~(size_t)255; };
  size_t zbt_b = align256((size_t)N_DIM * D_DIM * 2);
  size_t zft_b = align256((size_t)N_DIM * D_DIM * 4);
  size_t wb_b  = align256((size_t)M_DIM * D_DIM * 2);
  size_t ssq_b = align256((size_t)L_IT * C_CLS * N_DIM * 4);
  size_t out_b = align256((size_t)M_DIM * N_DIM * 2);

  if (zbt_b + zft_b + wb_b + ssq_b + out_b > ws_size) {
    hipMemsetAsync(d_out, 0, (size_t)D_DIM * N_DIM * 4, stream);  // clean-fail signal
    return;
  }

  char* p = (char*)d_ws;
  bf16_t* ZbT  = (bf16_t*)p; p += zbt_b;
  float*  ZfT  = (float*)p;  p += zft_b;
  bf16_t* Wb   = (bf16_t*)p; p += wb_b;
  float*  ssq  = (float*)p;  p += ssq_b;
  bf16_t* OUT_T= (bf16_t*)p;

  hipMemsetAsync(ssq, 0, (size_t)L_IT * C_CLS * N_DIM * 4, stream);
  init_zt<<<dim3(N_DIM / 32, D_DIM / 32), 256, 0, stream>>>(Zin, ZfT, ZbT);

  for (int l = 0; l < L_IT; ++l) {
    const float* Cs = Cslist + (size_t)l * C_CLS * D_DIM * D_DIM;
    const float* El = Elist  + (size_t)l * D_DIM * D_DIM;
    float* ssq_l = ssq + (size_t)l * C_CLS * N_DIM;

    pack_w<<<dim3(M_DIM * D_DIM / 4 / 256), 256, 0, stream>>>(
        (const float4*)Cs, (const float4*)El, (bf16x4*)Wb);

    gemm_persist<<<dim3(256), 512, 0, stream>>>(Wb, ZbT, OUT_T, ssq_l);
    update2<<<dim3(N_DIM / 4), 256, 0, stream>>>(
        OUT_T, N_DIM, ssq_l, gamma, eta, temperature, ZfT, ZbT, 0);
  }
  final_out<<<dim3(N_DIM / 32, D_DIM / 32), 256, 0, stream>>>(ZfT, (float*)d_out);
}

// Round 9
// 1257.942 us; speedup vs baseline: 1.0183x; 1.0183x over previous
//
#include <hip/hip_runtime.h>
#include <hip/hip_bf16.h>
#include <stdint.h>

#define D_DIM 1024
#define N_DIM 4096
#define C_CLS 10
#define L_IT 8
#define M_DIM 11264   // (C+1)*D
#define NBM 44        // M_DIM / 256

typedef __bf16 bf16_t;
typedef __bf16 bf16x8 __attribute__((ext_vector_type(8)));
typedef __bf16 bf16x4 __attribute__((ext_vector_type(4)));
typedef float  f32x4  __attribute__((ext_vector_type(4)));
typedef unsigned short u16x8 __attribute__((ext_vector_type(8)));

__device__ __forceinline__ float bf2f(uint16_t u) {
  union { uint32_t i; float f; } x; x.i = ((uint32_t)u) << 16; return x.f;
}

// ---------------- pack W = [Cs ; E] fp32 -> bf16 ----------------
__global__ __launch_bounds__(256) void pack_w(const float4* __restrict__ Cs,
                                              const float4* __restrict__ El,
                                              bf16x4* __restrict__ dst) {
  const int CS4 = C_CLS * D_DIM * D_DIM / 4;
  int i = blockIdx.x * 256 + threadIdx.x;
  float4 v = (i < CS4) ? Cs[i] : El[i - CS4];
  bf16x4 o;
  o[0] = (bf16_t)v.x; o[1] = (bf16_t)v.y; o[2] = (bf16_t)v.z; o[3] = (bf16_t)v.w;
  dst[i] = o;
}

// ---------------- layer-0 init ----------------
__global__ __launch_bounds__(256) void init_zt(const float* __restrict__ Zin,
                                               float* __restrict__ ZfT,
                                               bf16_t* __restrict__ ZbT) {
  __shared__ float tile[32][33];
  int tx = threadIdx.x & 31, ty = threadIdx.x >> 5;
  int nb = blockIdx.x, db = blockIdx.y;
  int n = nb * 32 + tx;
#pragma unroll
  for (int j = 0; j < 32; j += 8) {
    int d = db * 32 + ty + j;
    tile[ty + j][tx] = Zin[(size_t)d * N_DIM + n];
  }
  __syncthreads();
  int d2 = db * 32 + tx;
#pragma unroll
  for (int j = 0; j < 32; j += 8) {
    int n2 = nb * 32 + ty + j;
    float v = tile[tx][ty + j];
    ZfT[(size_t)n2 * D_DIM + d2] = v;
    ZbT[(size_t)n2 * D_DIM + d2] = (bf16_t)v;
  }
}

// ---------------- final transpose-out ----------------
__global__ __launch_bounds__(256) void final_out(const float* __restrict__ ZfT,
                                                 float* __restrict__ outp) {
  __shared__ float tile[32][33];
  int tx = threadIdx.x & 31, ty = threadIdx.x >> 5;
  int nb = blockIdx.x, db = blockIdx.y;
#pragma unroll
  for (int j = 0; j < 32; j += 8) {
    int n = nb * 32 + ty + j;
    int d = db * 32 + tx;
    tile[ty + j][tx] = ZfT[(size_t)n * D_DIM + d];
  }
  __syncthreads();
#pragma unroll
  for (int j = 0; j < 32; j += 8) {
    int d2 = db * 32 + ty + j;
    int n2 = nb * 32 + tx;
    outp[(size_t)d2 * N_DIM + n2] = tile[tx][ty + j];
  }
}

// ================= 256x256 GEMM, 4 phases / 2 K-tiles, compiler-scheduled LDS waits =================
// OUT_T[col][row] = (Wb * ZbT^T)^T. 512 thr = 8 waves (2Mx4N), BK=64, K=1024 (16 K-tiles).
// No lgkmcnt / sched_barrier pinning: compiler emits fine-grained ds_read->MFMA waits.
// Stage schedule (per iter, E=2it buf0, O=2it+1 buf1, N=2it+2, M=2it+3), all distances = 2 phases:
//   ph0(E qm0 + B): stage O.A1        | ph1(E qm1): stage N.{A0,B0,B1}
//   ph2(O qm0 + B): stage N.A1        | ph3(O qm1): stage M.{A0,B0,B1}
// vmcnt ledger (queue sim): uniform vmcnt(8) at each phase end; it==7: (8),(2),(0),none.

#define SA(buf, h, t) do {                                                              \
    _Pragma("unroll") for (int e_ = 0; e_ < 2; ++e_) {                                  \
      const bf16_t* s_ = Wb + aoff0[e_] + (size_t)(h) * 65536 + (size_t)(t) * 64;       \
      __builtin_amdgcn_global_load_lds(                                                 \
        (const __attribute__((address_space(1))) void*)s_,                              \
        (__attribute__((address_space(3))) void*)(lds + (buf)*16384 + (h)*8192 + dstslot[e_]), \
        16, 0, 0);                                                                      \
    } } while (0)

#define SBst(buf, h, t) do {                                                            \
    _Pragma("unroll") for (int e_ = 0; e_ < 2; ++e_) {                                  \
      const bf16_t* s_ = ZbT + boff0[e_] + (size_t)(h) * 32768 + (size_t)(t) * 64;      \
      __builtin_amdgcn_global_load_lds(                                                 \
        (const __attribute__((address_space(1))) void*)s_,                              \
        (__attribute__((address_space(3))) void*)(lds + 32768 + (buf)*16384 + (h)*8192 + dstslot[e_]), \
        16, 0, 0);                                                                      \
    } } while (0)

#define LOAD_A(buf, qm) do {                                                            \
    _Pragma("unroll") for (int f_ = 0; f_ < 4; ++f_)                                    \
      _Pragma("unroll") for (int kk_ = 0; kk_ < 2; ++kk_)                               \
        a[f_][kk_] = *(const bf16x8*)(lds + (buf)*16384 + (qm)*8192 + aRowBase + f_*1024 + sidx[kk_]); \
  } while (0)

#define LOAD_Bq(buf, qn, arr) do {                                                      \
    _Pragma("unroll") for (int f_ = 0; f_ < 2; ++f_)                                    \
      _Pragma("unroll") for (int kk_ = 0; kk_ < 2; ++kk_)                               \
        arr[f_][kk_] = *(const bf16x8*)(lds + 32768 + (buf)*16384 + (qn)*8192 + bRowBase + f_*1024 + sidx[kk_]); \
  } while (0)

#define MFMAQ(qm, qn, arr) do {                                                         \
    _Pragma("unroll") for (int mm_ = 0; mm_ < 4; ++mm_)                                 \
      _Pragma("unroll") for (int nn_ = 0; nn_ < 2; ++nn_)                               \
        _Pragma("unroll") for (int kk_ = 0; kk_ < 2; ++kk_)                             \
          acc[(qm)*4+mm_][(qn)*2+nn_] = __builtin_amdgcn_mfma_f32_16x16x32_bf16(        \
            a[mm_][kk_], arr[nn_][kk_], acc[(qm)*4+mm_][(qn)*2+nn_], 0, 0, 0);          \
  } while (0)

#define BAR   __builtin_amdgcn_s_barrier()
#define VM(n) asm volatile("s_waitcnt vmcnt(" #n ")" ::: "memory")
#define PRIO1 __builtin_amdgcn_s_setprio(1)
#define PRIO0 __builtin_amdgcn_s_setprio(0)

// phase: {ds loads | stages | BAR | MFMA (compiler-interleaved waits) | vm-wait | BAR}
#define PH(qm, LOADS, STAGES, WAIT) do {                                                \
    LOADS;                                                                              \
    STAGES;                                                                             \
    BAR;                                                                                \
    PRIO1;                                                                              \
    MFMAQ(qm, 0, b0);                                                                   \
    MFMAQ(qm, 1, b1);                                                                   \
    PRIO0;                                                                              \
    WAIT;                                                                               \
    BAR;                                                                                \
  } while (0)

__global__ __launch_bounds__(512, 2) void gemm_wz8(const bf16_t* __restrict__ Wb,
                                                   const bf16_t* __restrict__ ZbT,
                                                   bf16_t* __restrict__ OUT_T, int ldn,
                                                   float* __restrict__ ssq) {
  __shared__ __align__(16) bf16_t lds[65536];  // 128 KiB

  // T1: bijective XCD swizzle (m204); nwg=704 -> q=88,r=0 (clean chunks)
  int nwg = gridDim.x;
  int bid = blockIdx.x;
  int q = nwg >> 3, r = nwg & 7;
  int xcd = bid & 7, idx = bid >> 3;
  int swz = (xcd < r ? xcd * (q + 1) : r * (q + 1) + (xcd - r) * q) + idx;
  int bm = swz % NBM, bn = swz / NBM;
  int m0 = bm * 256, n0 = bn * 256;

  int tid = threadIdx.x;
  int wave = tid >> 6, lane = tid & 63;
  int wrow = wave >> 2, wcol = wave & 3;
  int lm = lane & 15, lks = lane >> 4;
  int sw = lm & 7;

  size_t aoff0[2], boff0[2];
  int dstslot[2];
#pragma unroll
  for (int e = 0; e < 2; ++e) {
    int j = e * 512 + tid;
    int rih = j >> 3, sl = j & 7;
    int sg = sl ^ (rih & 7);                       // pre-swizzled global 16B slot
    int arow = (rih & 63) + ((rih >> 6) << 7);     // A halves: {0-63,128-191}/{+64}
    int brow = (rih & 31) + ((rih >> 5) << 6);     // B halves: 32-row interleave
    aoff0[e] = (size_t)(m0 + arow) * 1024 + sg * 8;
    boff0[e] = (size_t)(n0 + brow) * 1024 + sg * 8;
    dstslot[e] = e * 4096 + wave * 512;
  }

  int aRowBase = (wrow * 64 + lm) * 64;
  int bRowBase = (wcol * 32 + lm) * 64;
  int sidx[2] = { ((0 + lks) ^ sw) * 8, ((4 + lks) ^ sw) * 8 };

  f32x4 acc[8][4] = {};
  bf16x8 a[4][2], b0[2][2], b1[2][2];

  // prologue: T0.{A0,B0,B1}(6) ; T0.A1(2) ; T1.{A0,B0,B1}(6). Drain first group.
  SA(0, 0, 0); SBst(0, 0, 0); SBst(0, 1, 0);
  SA(0, 1, 0);
  SA(1, 0, 1); SBst(1, 0, 1); SBst(1, 1, 1);
  VM(8);
  BAR;

  for (int it = 0; it < 8; ++it) {
    int tO = 2 * it + 1, tN = 2 * it + 2, tM = 2 * it + 3;
    bool st = (it < 7);

    // ph0: E qm0 + both B quadrants; stage O.A1
    PH(0,
       LOAD_A(0, 0); LOAD_Bq(0, 0, b0); LOAD_Bq(0, 1, b1),
       SA(1, 1, tO),
       VM(8));

    // ph1: E qm1; stage N.{A0,B0,B1}
    if (st) {
      PH(1, LOAD_A(0, 1), SA(0, 0, tN); SBst(0, 0, tN); SBst(0, 1, tN), VM(8));
    } else {
      PH(1, LOAD_A(0, 1), , VM(2));
    }

    // ph2: O qm0 + both B quadrants; stage N.A1
    if (st) {
      PH(0, LOAD_A(1, 0); LOAD_Bq(1, 0, b0); LOAD_Bq(1, 1, b1), SA(0, 1, tN), VM(8));
    } else {
      PH(0, LOAD_A(1, 0); LOAD_Bq(1, 0, b0); LOAD_Bq(1, 1, b1), , VM(0));
    }

    // ph3: O qm1; stage M.{A0,B0,B1}
    if (st) {
      PH(1, LOAD_A(1, 1), SA(1, 0, tM); SBst(1, 0, tM); SBst(1, 1, tM), VM(8));
    } else {
      PH(1, LOAD_A(1, 1), , );
    }
  }

  // C-write (transposed): OUT_T[col][row]; 4 acc rows contiguous -> 8B store
#pragma unroll
  for (int mf = 0; mf < 8; ++mf)
#pragma unroll
    for (int nf = 0; nf < 4; ++nf) {
      int col = n0 + wcol * 64 + nf * 16 + lm;
      int row = m0 + wrow * 128 + mf * 16 + lks * 4;
      bf16x4 v;
#pragma unroll
      for (int rr = 0; rr < 4; ++rr) v[rr] = (bf16_t)acc[mf][nf][rr];
      *(bf16x4*)(OUT_T + (size_t)col * M_DIM + row) = v;
    }

  // fused per-class column sum-of-squares (class blocks only; E rows skip)
  if (m0 < C_CLS * 1024) {
    int c = m0 >> 10;
#pragma unroll
    for (int nf = 0; nf < 4; ++nf) {
      float v = 0.f;
#pragma unroll
      for (int mf = 0; mf < 8; ++mf)
#pragma unroll
        for (int rr = 0; rr < 4; ++rr)
          v += acc[mf][nf][rr] * acc[mf][nf][rr];
      v += __shfl_xor(v, 16);
      v += __shfl_xor(v, 32);
      if (lks == 0)
        atomicAdd(&ssq[(size_t)c * ldn + n0 + wcol * 64 + nf * 16 + lm], v);
    }
  }
}

// ---------------- fused softmax + update + normalize + ZbT emit ----------------
__global__ __launch_bounds__(256) void update2(const bf16_t* __restrict__ OUT_T, int Nc,
                                               const float* __restrict__ ssq,
                                               const float* __restrict__ gamma,
                                               const float* __restrict__ etap,
                                               const float* __restrict__ tempr,
                                               float* __restrict__ ZfT,
                                               bf16_t* __restrict__ ZbT,
                                               int n_off) {
  int wv = threadIdx.x >> 6, lane = threadIdx.x & 63;
  int nl = blockIdx.x * 4 + wv;
  if (nl >= Nc) return;
  int n = n_off + nl;
  float eta = etap[0], invT = 1.0f / tempr[0];

  float s[C_CLS], m = -1e30f;
#pragma unroll
  for (int c = 0; c < C_CLS; ++c) {
    float sim = -sqrtf(ssq[(size_t)c * Nc + nl]);
    s[c] = sim;
    m = fmaxf(m, sim);
  }
  float sum = 0.f;
#pragma unroll
  for (int c = 0; c < C_CLS; ++c) {
    float e = __expf((s[c] - m) * invT);
    s[c] = e;
    sum += e;
  }
  float invsum = 1.0f / sum;
  float gP[C_CLS];
#pragma unroll
  for (int c = 0; c < C_CLS; ++c) gP[c] = gamma[c] * s[c] * invsum;

  const u16x8* ob = (const u16x8*)(OUT_T + (size_t)nl * M_DIM) + lane * 2;
  float term[16] = {};
#pragma unroll
  for (int c = 0; c < C_CLS; ++c) {
    u16x8 v0 = ob[c * 128], v1 = ob[c * 128 + 1];
#pragma unroll
    for (int j = 0; j < 8; ++j) {
      term[j]     += gP[c] * bf2f(v0[j]);
      term[8 + j] += gP[c] * bf2f(v1[j]);
    }
  }
  u16x8 g0 = ob[C_CLS * 128], g1 = ob[C_CLS * 128 + 1];

  const f32x4* zp = (const f32x4*)(ZfT + (size_t)n * D_DIM) + lane * 4;
  f32x4 z[4] = { zp[0], zp[1], zp[2], zp[3] };

  float zn[16];
  float ss = 0.f;
#pragma unroll
  for (int j = 0; j < 16; ++j) {
    float g = bf2f(j < 8 ? g0[j & 7] : g1[j & 7]);
    float v = z[j >> 2][j & 3] + eta * (g - term[j]);
    zn[j] = v;
    ss += v * v;
  }
#pragma unroll
  for (int k = 1; k < 64; k <<= 1) ss += __shfl_xor(ss, k);
  float inv = rsqrtf(ss);

  f32x4* zo = (f32x4*)(ZfT + (size_t)n * D_DIM) + lane * 4;
  bf16x8* bo = (bf16x8*)(ZbT + (size_t)n * D_DIM) + lane * 2;
#pragma unroll
  for (int q4 = 0; q4 < 4; ++q4) {
    f32x4 o;
#pragma unroll
    for (int j = 0; j < 4; ++j) o[j] = zn[q4 * 4 + j] * inv;
    zo[q4] = o;
  }
#pragma unroll
  for (int h = 0; h < 2; ++h) {
    bf16x8 o;
#pragma unroll
    for (int j = 0; j < 8; ++j) o[j] = (bf16_t)(zn[h * 8 + j] * inv);
    bo[h] = o;
  }
}

extern "C" void kernel_launch(void* const* d_in, const int* in_sizes, int n_in,
                              void* d_out, int out_size, void* d_ws, size_t ws_size,
                              hipStream_t stream) {
  (void)in_sizes; (void)n_in; (void)out_size;
  const float* Zin        = (const float*)d_in[0];
  const float* Elist      = (const float*)d_in[1];
  const float* Cslist     = (const float*)d_in[2];
  const float* gamma      = (const float*)d_in[3];
  const float* eta        = (const float*)d_in[4];
  const float* temperature= (const float*)d_in[5];

  auto align256 = [](size_t x) { return (x + 255) & ~(size_t)255; };
  size_t zbt_b = align256((size_t)N_DIM * D_DIM * 2);
  size_t zft_b = align256((size_t)N_DIM * D_DIM * 4);
  size_t wb_b  = align256((size_t)M_DIM * D_DIM * 2);
  size_t ssq_b = align256((size_t)L_IT * C_CLS * N_DIM * 4);
  size_t out_b = align256((size_t)M_DIM * N_DIM * 2);

  if (zbt_b + zft_b + wb_b + ssq_b + out_b > ws_size) {
    hipMemsetAsync(d_out, 0, (size_t)D_DIM * N_DIM * 4, stream);  // clean-fail signal
    return;
  }

  char* p = (char*)d_ws;
  bf16_t* ZbT  = (bf16_t*)p; p += zbt_b;
  float*  ZfT  = (float*)p;  p += zft_b;
  bf16_t* Wb   = (bf16_t*)p; p += wb_b;
  float*  ssq  = (float*)p;  p += ssq_b;
  bf16_t* OUT_T= (bf16_t*)p;

  hipMemsetAsync(ssq, 0, (size_t)L_IT * C_CLS * N_DIM * 4, stream);
  init_zt<<<dim3(N_DIM / 32, D_DIM / 32), 256, 0, stream>>>(Zin, ZfT, ZbT);

  for (int l = 0; l < L_IT; ++l) {
    const float* Cs = Cslist + (size_t)l * C_CLS * D_DIM * D_DIM;
    const float* El = Elist  + (size_t)l * D_DIM * D_DIM;
    float* ssq_l = ssq + (size_t)l * C_CLS * N_DIM;

    pack_w<<<dim3(M_DIM * D_DIM / 4 / 256), 256, 0, stream>>>(
        (const float4*)Cs, (const float4*)El, (bf16x4*)Wb);

    gemm_wz8<<<dim3(NBM * (N_DIM / 256)), 512, 0, stream>>>(
        Wb, ZbT, OUT_T, N_DIM, ssq_l);
    update2<<<dim3(N_DIM / 4), 256, 0, stream>>>(
        OUT_T, N_DIM, ssq_l, gamma, eta, temperature, ZfT, ZbT, 0);
  }
  final_out<<<dim3(N_DIM / 32, D_DIM / 32), 256, 0, stream>>>(ZfT, (float*)d_out);
}

// Round 10
// 1244.198 us; speedup vs baseline: 1.0296x; 1.0110x over previous
//
#include <hip/hip_runtime.h>
#include <hip/hip_bf16.h>
#include <stdint.h>

#define D_DIM 1024
#define N_DIM 4096
#define C_CLS 10
#define L_IT 8
#define M_DIM 11264   // (C+1)*D
#define NBM 44        // M_DIM / 256

typedef __bf16 bf16_t;
typedef __bf16 bf16x8 __attribute__((ext_vector_type(8)));
typedef __bf16 bf16x4 __attribute__((ext_vector_type(4)));
typedef float  f32x4  __attribute__((ext_vector_type(4)));
typedef unsigned short u16x8 __attribute__((ext_vector_type(8)));

__device__ __forceinline__ float bf2f(uint16_t u) {
  union { uint32_t i; float f; } x; x.i = ((uint32_t)u) << 16; return x.f;
}

// ---------------- pack W = [Cs ; E] fp32 -> bf16 ----------------
__global__ __launch_bounds__(256) void pack_w(const float4* __restrict__ Cs,
                                              const float4* __restrict__ El,
                                              bf16x4* __restrict__ dst) {
  const int CS4 = C_CLS * D_DIM * D_DIM / 4;
  int i = blockIdx.x * 256 + threadIdx.x;
  float4 v = (i < CS4) ? Cs[i] : El[i - CS4];
  bf16x4 o;
  o[0] = (bf16_t)v.x; o[1] = (bf16_t)v.y; o[2] = (bf16_t)v.z; o[3] = (bf16_t)v.w;
  dst[i] = o;
}

// ---------------- layer-0 init ----------------
__global__ __launch_bounds__(256) void init_zt(const float* __restrict__ Zin,
                                               float* __restrict__ ZfT,
                                               bf16_t* __restrict__ ZbT) {
  __shared__ float tile[32][33];
  int tx = threadIdx.x & 31, ty = threadIdx.x >> 5;
  int nb = blockIdx.x, db = blockIdx.y;
  int n = nb * 32 + tx;
#pragma unroll
  for (int j = 0; j < 32; j += 8) {
    int d = db * 32 + ty + j;
    tile[ty + j][tx] = Zin[(size_t)d * N_DIM + n];
  }
  __syncthreads();
  int d2 = db * 32 + tx;
#pragma unroll
  for (int j = 0; j < 32; j += 8) {
    int n2 = nb * 32 + ty + j;
    float v = tile[tx][ty + j];
    ZfT[(size_t)n2 * D_DIM + d2] = v;
    ZbT[(size_t)n2 * D_DIM + d2] = (bf16_t)v;
  }
}

// ---------------- final transpose-out ----------------
__global__ __launch_bounds__(256) void final_out(const float* __restrict__ ZfT,
                                                 float* __restrict__ outp) {
  __shared__ float tile[32][33];
  int tx = threadIdx.x & 31, ty = threadIdx.x >> 5;
  int nb = blockIdx.x, db = blockIdx.y;
#pragma unroll
  for (int j = 0; j < 32; j += 8) {
    int n = nb * 32 + ty + j;
    int d = db * 32 + tx;
    tile[ty + j][tx] = ZfT[(size_t)n * D_DIM + d];
  }
  __syncthreads();
#pragma unroll
  for (int j = 0; j < 32; j += 8) {
    int d2 = db * 32 + ty + j;
    int n2 = nb * 32 + tx;
    outp[(size_t)d2 * N_DIM + n2] = tile[tx][ty + j];
  }
}

// ================= 256x256 GEMM — literal m201 8-phase template =================
// OUT_T[col][row] = (Wb * ZbT^T)^T. 512 thr = 8 waves (2Mx4N), BK=64, K=1024 (16 K-tiles).
// Per phase: {ds-reads (<=12) | 1 half-tile stage (2 gload_lds) | [lgkm(8) if 12 reads]
//   | BAR | lgkm(0) | setprio1 | 16 MFMA (one C-quadrant x K=64) | setprio0 | [vm] | BAR}.
// vmcnt(6) ONLY at ph4/ph8 (3 half-tiles in flight invariant). Stage slots:
//   p1:O.A1  p2:N.A0  p3:N.B0  p4:N.B1  p5:N.A1  p6:M.A0  p7:M.B0  p8:M.B1
// (E=2it buf0, O=2it+1 buf1, N=E+2, M=O+2). Region-death check: every staged region's
// last ds_read is >=1 phase earlier. Tail (it==7): stages off, ph4 -> vmcnt(0).

#define SA(buf, h, t) do {                                                              \
    _Pragma("unroll") for (int e_ = 0; e_ < 2; ++e_) {                                  \
      const bf16_t* s_ = Wb + aoff0[e_] + (size_t)(h) * 65536 + (size_t)(t) * 64;       \
      __builtin_amdgcn_global_load_lds(                                                 \
        (const __attribute__((address_space(1))) void*)s_,                              \
        (__attribute__((address_space(3))) void*)(lds + (buf)*16384 + (h)*8192 + dstslot[e_]), \
        16, 0, 0);                                                                      \
    } } while (0)

#define SBst(buf, h, t) do {                                                            \
    _Pragma("unroll") for (int e_ = 0; e_ < 2; ++e_) {                                  \
      const bf16_t* s_ = ZbT + boff0[e_] + (size_t)(h) * 32768 + (size_t)(t) * 64;      \
      __builtin_amdgcn_global_load_lds(                                                 \
        (const __attribute__((address_space(1))) void*)s_,                              \
        (__attribute__((address_space(3))) void*)(lds + 32768 + (buf)*16384 + (h)*8192 + dstslot[e_]), \
        16, 0, 0);                                                                      \
    } } while (0)

#define LOAD_A(buf, qm) do {                                                            \
    _Pragma("unroll") for (int f_ = 0; f_ < 4; ++f_)                                    \
      _Pragma("unroll") for (int kk_ = 0; kk_ < 2; ++kk_)                               \
        a[f_][kk_] = *(const bf16x8*)(lds + (buf)*16384 + (qm)*8192 + aRowBase + f_*1024 + sidx[kk_]); \
  } while (0)

#define LOAD_Bq(buf, qn, arr) do {                                                      \
    _Pragma("unroll") for (int f_ = 0; f_ < 2; ++f_)                                    \
      _Pragma("unroll") for (int kk_ = 0; kk_ < 2; ++kk_)                               \
        arr[f_][kk_] = *(const bf16x8*)(lds + 32768 + (buf)*16384 + (qn)*8192 + bRowBase + f_*1024 + sidx[kk_]); \
  } while (0)

#define MFMAQ(qm, qn, arr) do {                                                         \
    _Pragma("unroll") for (int mm_ = 0; mm_ < 4; ++mm_)                                 \
      _Pragma("unroll") for (int nn_ = 0; nn_ < 2; ++nn_)                               \
        _Pragma("unroll") for (int kk_ = 0; kk_ < 2; ++kk_)                             \
          acc[(qm)*4+mm_][(qn)*2+nn_] = __builtin_amdgcn_mfma_f32_16x16x32_bf16(        \
            a[mm_][kk_], arr[nn_][kk_], acc[(qm)*4+mm_][(qn)*2+nn_], 0, 0, 0);          \
  } while (0)

#define BAR   __builtin_amdgcn_s_barrier()
#define VM(n) asm volatile("s_waitcnt vmcnt(" #n ")" ::: "memory")
#define LGKM8 asm volatile("s_waitcnt lgkmcnt(8)" ::: "memory")
#define LGKM0 asm volatile("s_waitcnt lgkmcnt(0)" ::: "memory")
#define PRIO1 __builtin_amdgcn_s_setprio(1)
#define PRIO0 __builtin_amdgcn_s_setprio(0)

// m201 phase: loads | stage | [pre-bar lgkm] | BAR | lgkm0 | prio MFMA prio | [vm] | BAR
#define PH8(qm, qn, arr, LOADS, STAGES, PREBAR, POSTMFMA) do {                          \
    LOADS;                                                                              \
    STAGES;                                                                             \
    PREBAR;                                                                             \
    BAR;                                                                                \
    LGKM0;                                                                              \
    PRIO1;                                                                              \
    MFMAQ(qm, qn, arr);                                                                 \
    PRIO0;                                                                              \
    POSTMFMA;                                                                           \
    BAR;                                                                                \
  } while (0)

__global__ __launch_bounds__(512, 2) void gemm_wz8(const bf16_t* __restrict__ Wb,
                                                   const bf16_t* __restrict__ ZbT,
                                                   bf16_t* __restrict__ OUT_T, int ldn,
                                                   float* __restrict__ ssq) {
  __shared__ __align__(16) bf16_t lds[65536];  // 128 KiB

  // T1: bijective XCD swizzle (m204); nwg=704 -> q=88,r=0
  int nwg = gridDim.x;
  int bid = blockIdx.x;
  int q = nwg >> 3, r = nwg & 7;
  int xcd = bid & 7, idx = bid >> 3;
  int swz = (xcd < r ? xcd * (q + 1) : r * (q + 1) + (xcd - r) * q) + idx;
  int bm = swz % NBM, bn = swz / NBM;
  int m0 = bm * 256, n0 = bn * 256;

  int tid = threadIdx.x;
  int wave = tid >> 6, lane = tid & 63;
  int wrow = wave >> 2, wcol = wave & 3;
  int lm = lane & 15, lks = lane >> 4;
  int sw = lm & 7;

  size_t aoff0[2], boff0[2];
  int dstslot[2];
#pragma unroll
  for (int e = 0; e < 2; ++e) {
    int j = e * 512 + tid;
    int rih = j >> 3, sl = j & 7;
    int sg = sl ^ (rih & 7);                       // pre-swizzled global 16B slot
    int arow = (rih & 63) + ((rih >> 6) << 7);     // A halves: {0-63,128-191}/{+64}
    int brow = (rih & 31) + ((rih >> 5) << 6);     // B halves: 32-row interleave
    aoff0[e] = (size_t)(m0 + arow) * 1024 + sg * 8;
    boff0[e] = (size_t)(n0 + brow) * 1024 + sg * 8;
    dstslot[e] = e * 4096 + wave * 512;
  }

  int aRowBase = (wrow * 64 + lm) * 64;
  int bRowBase = (wcol * 32 + lm) * 64;
  int sidx[2] = { ((0 + lks) ^ sw) * 8, ((4 + lks) ^ sw) * 8 };

  f32x4 acc[8][4] = {};
  bf16x8 a[4][2], b0[2][2], b1[2][2];

  // prologue: issue E0.{A0,B0,B1,A1} then O0.{A0,B0,B1}; vmcnt(6) completes E0 fully.
  SA(0, 0, 0); SBst(0, 0, 0); SBst(0, 1, 0); SA(0, 1, 0);
  SA(1, 0, 1); SBst(1, 0, 1); SBst(1, 1, 1);
  VM(6);
  BAR;

  for (int it = 0; it < 8; ++it) {
    int tO = 2 * it + 1, tN = 2 * it + 2, tM = 2 * it + 3;
    bool st = (it < 7);

    // p1: E qm0 qn0 (12 reads); stage O.A1
    PH8(0, 0, b0, LOAD_A(0, 0); LOAD_Bq(0, 0, b0), SA(1, 1, tO), LGKM8, );
    // p2: E qm0 qn1 (4 reads); stage N.A0
    PH8(0, 1, b1, LOAD_Bq(0, 1, b1), { if (st) SA(0, 0, tN); }, , );
    // p3: E qm1 qn0 (8 reads); stage N.B0
    PH8(1, 0, b0, LOAD_A(0, 1), { if (st) SBst(0, 0, tN); }, , );
    // p4: E qm1 qn1 (0 reads); stage N.B1; vmcnt
    PH8(1, 1, b1, , { if (st) SBst(0, 1, tN); }, ,
        { if (st) { VM(6); } else { VM(0); } });
    // p5: O qm0 qn0 (12 reads); stage N.A1
    PH8(0, 0, b0, LOAD_A(1, 0); LOAD_Bq(1, 0, b0), { if (st) SA(0, 1, tN); }, LGKM8, );
    // p6: O qm0 qn1 (4 reads); stage M.A0
    PH8(0, 1, b1, LOAD_Bq(1, 1, b1), { if (st) SA(1, 0, tM); }, , );
    // p7: O qm1 qn0 (8 reads); stage M.B0
    PH8(1, 0, b0, LOAD_A(1, 1), { if (st) SBst(1, 0, tM); }, , );
    // p8: O qm1 qn1 (0 reads); stage M.B1; vmcnt
    PH8(1, 1, b1, , { if (st) SBst(1, 1, tM); }, , { if (st) VM(6); });
  }

  // C-write (transposed): OUT_T[col][row]; 4 acc rows contiguous -> 8B store
#pragma unroll
  for (int mf = 0; mf < 8; ++mf)
#pragma unroll
    for (int nf = 0; nf < 4; ++nf) {
      int col = n0 + wcol * 64 + nf * 16 + lm;
      int row = m0 + wrow * 128 + mf * 16 + lks * 4;
      bf16x4 v;
#pragma unroll
      for (int rr = 0; rr < 4; ++rr) v[rr] = (bf16_t)acc[mf][nf][rr];
      *(bf16x4*)(OUT_T + (size_t)col * M_DIM + row) = v;
    }

  // fused per-class column sum-of-squares (class blocks only; E rows skip)
  if (m0 < C_CLS * 1024) {
    int c = m0 >> 10;
#pragma unroll
    for (int nf = 0; nf < 4; ++nf) {
      float v = 0.f;
#pragma unroll
      for (int mf = 0; mf < 8; ++mf)
#pragma unroll
        for (int rr = 0; rr < 4; ++rr)
          v += acc[mf][nf][rr] * acc[mf][nf][rr];
      v += __shfl_xor(v, 16);
      v += __shfl_xor(v, 32);
      if (lks == 0)
        atomicAdd(&ssq[(size_t)c * ldn + n0 + wcol * 64 + nf * 16 + lm], v);
    }
  }
}

// ---------------- fused softmax + update + normalize + ZbT emit ----------------
__global__ __launch_bounds__(256) void update2(const bf16_t* __restrict__ OUT_T, int Nc,
                                               const float* __restrict__ ssq,
                                               const float* __restrict__ gamma,
                                               const float* __restrict__ etap,
                                               const float* __restrict__ tempr,
                                               float* __restrict__ ZfT,
                                               bf16_t* __restrict__ ZbT,
                                               int n_off) {
  int wv = threadIdx.x >> 6, lane = threadIdx.x & 63;
  int nl = blockIdx.x * 4 + wv;
  if (nl >= Nc) return;
  int n = n_off + nl;
  float eta = etap[0], invT = 1.0f / tempr[0];

  float s[C_CLS], m = -1e30f;
#pragma unroll
  for (int c = 0; c < C_CLS; ++c) {
    float sim = -sqrtf(ssq[(size_t)c * Nc + nl]);
    s[c] = sim;
    m = fmaxf(m, sim);
  }
  float sum = 0.f;
#pragma unroll
  for (int c = 0; c < C_CLS; ++c) {
    float e = __expf((s[c] - m) * invT);
    s[c] = e;
    sum += e;
  }
  float invsum = 1.0f / sum;
  float gP[C_CLS];
#pragma unroll
  for (int c = 0; c < C_CLS; ++c) gP[c] = gamma[c] * s[c] * invsum;

  const u16x8* ob = (const u16x8*)(OUT_T + (size_t)nl * M_DIM) + lane * 2;
  float term[16] = {};
#pragma unroll
  for (int c = 0; c < C_CLS; ++c) {
    u16x8 v0 = ob[c * 128], v1 = ob[c * 128 + 1];
#pragma unroll
    for (int j = 0; j < 8; ++j) {
      term[j]     += gP[c] * bf2f(v0[j]);
      term[8 + j] += gP[c] * bf2f(v1[j]);
    }
  }
  u16x8 g0 = ob[C_CLS * 128], g1 = ob[C_CLS * 128 + 1];

  const f32x4* zp = (const f32x4*)(ZfT + (size_t)n * D_DIM) + lane * 4;
  f32x4 z[4] = { zp[0], zp[1], zp[2], zp[3] };

  float zn[16];
  float ss = 0.f;
#pragma unroll
  for (int j = 0; j < 16; ++j) {
    float g = bf2f(j < 8 ? g0[j & 7] : g1[j & 7]);
    float v = z[j >> 2][j & 3] + eta * (g - term[j]);
    zn[j] = v;
    ss += v * v;
  }
#pragma unroll
  for (int k = 1; k < 64; k <<= 1) ss += __shfl_xor(ss, k);
  float inv = rsqrtf(ss);

  f32x4* zo = (f32x4*)(ZfT + (size_t)n * D_DIM) + lane * 4;
  bf16x8* bo = (bf16x8*)(ZbT + (size_t)n * D_DIM) + lane * 2;
#pragma unroll
  for (int q4 = 0; q4 < 4; ++q4) {
    f32x4 o;
#pragma unroll
    for (int j = 0; j < 4; ++j) o[j] = zn[q4 * 4 + j] * inv;
    zo[q4] = o;
  }
#pragma unroll
  for (int h = 0; h < 2; ++h) {
    bf16x8 o;
#pragma unroll
    for (int j = 0; j < 8; ++j) o[j] = (bf16_t)(zn[h * 8 + j] * inv);
    bo[h] = o;
  }
}

extern "C" void kernel_launch(void* const* d_in, const int* in_sizes, int n_in,
                              void* d_out, int out_size, void* d_ws, size_t ws_size,
                              hipStream_t stream) {
  (void)in_sizes; (void)n_in; (void)out_size;
  const float* Zin        = (const float*)d_in[0];
  const float* Elist      = (const float*)d_in[1];
  const float* Cslist     = (const float*)d_in[2];
  const float* gamma      = (const float*)d_in[3];
  const float* eta        = (const float*)d_in[4];
  const float* temperature= (const float*)d_in[5];

  auto align256 = [](size_t x) { return (x + 255) & ~(size_t)255; };
  size_t zbt_b = align256((size_t)N_DIM * D_DIM * 2);
  size_t zft_b = align256((size_t)N_DIM * D_DIM * 4);
  size_t wb_b  = align256((size_t)M_DIM * D_DIM * 2);
  size_t ssq_b = align256((size_t)L_IT * C_CLS * N_DIM * 4);
  size_t out_b = align256((size_t)M_DIM * N_DIM * 2);

  if (zbt_b + zft_b + wb_b + ssq_b + out_b > ws_size) {
    hipMemsetAsync(d_out, 0, (size_t)D_DIM * N_DIM * 4, stream);  // clean-fail signal
    return;
  }

  char* p = (char*)d_ws;
  bf16_t* ZbT  = (bf16_t*)p; p += zbt_b;
  float*  ZfT  = (float*)p;  p += zft_b;
  bf16_t* Wb   = (bf16_t*)p; p += wb_b;
  float*  ssq  = (float*)p;  p += ssq_b;
  bf16_t* OUT_T= (bf16_t*)p;

  hipMemsetAsync(ssq, 0, (size_t)L_IT * C_CLS * N_DIM * 4, stream);
  init_zt<<<dim3(N_DIM / 32, D_DIM / 32), 256, 0, stream>>>(Zin, ZfT, ZbT);

  for (int l = 0; l < L_IT; ++l) {
    const float* Cs = Cslist + (size_t)l * C_CLS * D_DIM * D_DIM;
    const float* El = Elist  + (size_t)l * D_DIM * D_DIM;
    float* ssq_l = ssq + (size_t)l * C_CLS * N_DIM;

    pack_w<<<dim3(M_DIM * D_DIM / 4 / 256), 256, 0, stream>>>(
        (const float4*)Cs, (const float4*)El, (bf16x4*)Wb);

    gemm_wz8<<<dim3(NBM * (N_DIM / 256)), 512, 0, stream>>>(
        Wb, ZbT, OUT_T, N_DIM, ssq_l);
    update2<<<dim3(N_DIM / 4), 256, 0, stream>>>(
        OUT_T, N_DIM, ssq_l, gamma, eta, temperature, ZfT, ZbT, 0);
  }
  final_out<<<dim3(N_DIM / 32, D_DIM / 32), 256, 0, stream>>>(ZfT, (float*)d_out);
}